// Round 1
// baseline (1380.041 us; speedup 1.0000x reference)
//
#include <hip/hip_runtime.h>
#include <hip/hip_fp16.h>

#define T_SEQ 2048
#define HID   50
#define VOC   13
#define NT    16      // 16 N-tiles of 16 cols = 256 cols: col = (u>>4)*64 + gate*16 + (u&15)
#define KP    64      // k: 0..49 = h, 50..63 = zero pad (token+bias folded into Ttab C-add)
#define NTHR  256     // 4 waves/block, 1 batch row per wave
#define NBLK  512     // 2048 rows / 4

typedef __attribute__((ext_vector_type(8))) _Float16      half8;
typedef __attribute__((ext_vector_type(4))) float         f32x4;
typedef __attribute__((ext_vector_type(4))) unsigned int  uint4v;

__device__ __forceinline__ ushort f16b(float f) {
    return __half_as_ushort(__float2half(f));   // RNE
}
__device__ __forceinline__ float rcp_(float x) {
    return __builtin_amdgcn_rcpf(x);
}
__device__ __forceinline__ float sigm(float x) {
    return rcp_(1.f + __expf(-x));
}
__device__ __forceinline__ float tanh_(float x) {
    return fmaf(2.f, rcp_(1.f + __expf(-2.f * x)), -1.f);
}
// 3-cndmask select among 4 values by per-lane q in [0,4)
__device__ __forceinline__ float sel4(int q, float a, float b, float c, float d) {
    float x = (q == 0) ? a : b;
    float y = (q == 2) ? c : d;
    return (q < 2) ? x : y;
}

// Bm [256 cols][64 k] f16: Bm[col][k] = W_hh[g*50+u][k] for k<50, u<50; else 0.
//   col decode: ublk=col>>6, g=(col>>4)&3, ulan=col&15, u=ublk*16+ulan.
// Tt [13 v][64 lane][4 gate] f32: embed[v]·W_ih[row] + b_ih[row] + b_hh[row], row=g*50+lane.
__global__ void build_tabs(const float* __restrict__ embed,
                           const float* __restrict__ Wih,
                           const float* __restrict__ Whh,
                           const float* __restrict__ bih,
                           const float* __restrict__ bhh,
                           ushort* __restrict__ Bm,
                           float*  __restrict__ Tt) {
    int idx = blockIdx.x * blockDim.x + threadIdx.x;
    if (idx < NT * 16 * KP) {
        int col = idx >> 6, k = idx & 63;
        int u = ((col >> 6) << 4) | (col & 15);
        int g = (col >> 4) & 3;
        ushort val = 0;
        if (u < HID && k < HID) val = f16b(Whh[(g * HID + u) * HID + k]);
        Bm[idx] = val;
        return;
    }
    idx -= NT * 16 * KP;
    if (idx < VOC * 256) {
        int v = idx >> 8, l = (idx >> 2) & 63, g = idx & 3;
        float t = 0.f;
        if (l < HID) {
            int r = g * HID + l;
            for (int e = 0; e < HID; ++e)
                t = fmaf(embed[v * HID + e], Wih[r * HID + e], t);
            t += bih[r] + bhh[r];
        }
        Tt[idx] = t;
    }
}

// One batch row per wave. No __syncthreads in the time loop, no LDS round-trips:
//  - A rows broadcast h -> every lane holds every tile's gate value for its own column
//  - gate gather = 12 cndmask; token/bias via f32 C-add from prefetched LDS table
//  - h scatter back to A-frags = 16 parallel ds_bpermute (single LDS-pipe pass)
__global__ __launch_bounds__(NTHR, 2) void lstm_wave(
    const int*    __restrict__ x,
    const ushort* __restrict__ Bm,
    const float*  __restrict__ Ttg,
    const float*  __restrict__ W1,
    const float*  __restrict__ b1,
    const float*  __restrict__ W2,
    const float*  __restrict__ b2,
    float*        __restrict__ out)
{
    const int t   = threadIdx.x;
    const int w   = t >> 6;
    const int l   = t & 63;
    const int q   = l >> 4;
    const int c16 = l & 15;

    __shared__ __align__(16) float Tt[VOC * 256];   // [v][lane][gate] 13.0 KiB
    __shared__ float hbuf[4][64];
    __shared__ float zbuf[4][64];

    for (int i = t; i < VOC * 256; i += NTHR) Tt[i] = Ttg[i];

    // B resident in registers: 32 x half8 = 128 VGPRs
    half8 bf0[NT], bf1[NT];
    {
        const ushort* bp = Bm + c16 * KP + q * 8;
        #pragma unroll
        for (int j = 0; j < NT; ++j) {
            bf0[j] = *(const half8*)(bp + j * 16 * KP);
            bf1[j] = *(const half8*)(bp + j * 16 * KP + 32);
        }
    }

    const int  row = blockIdx.x * 4 + w;
    const long xb  = (long)row * T_SEQ;

    int tok0 = x[xb + 0];
    int vA   = x[xb + 1];
    int vB   = x[xb + 2];

    __syncthreads();   // Tt ready (the only block-wide barrier before epilogue)

    f32x4 tt = *(const f32x4*)(Tt + tok0 * 256 + l * 4);

    half8 a0, a1;
    {
        union { uint4v u; half8 h; } zc;
        zc.u = (uint4v){0u, 0u, 0u, 0u};
        a0 = zc.h; a1 = zc.h;        // h(0) = 0
    }
    float c = 0.f, h = 0.f;
    const int ab = q * 32;           // bpermute byte addr base: lane q*8+e

    #pragma unroll 1
    for (int step = 0; step < T_SEQ; ++step) {
        // ---- prefetch (off critical chain): next token's table row + token t+3
        f32x4 ttn = *(const f32x4*)(Tt + vA * 256 + l * 4);
        int it = step + 3; if (it > T_SEQ - 1) it = T_SEQ - 1;
        int vN = x[xb + it];

        // ---- gates: 16 tiles x (2 chained MFMAs); keep only scalar per tile
        const f32x4 zz = {0.f, 0.f, 0.f, 0.f};
        float s[NT];
        #pragma unroll
        for (int j = 0; j < NT; ++j) {
            f32x4 zj = __builtin_amdgcn_mfma_f32_16x16x32_f16(a0, bf0[j], zz, 0, 0, 0);
            zj = __builtin_amdgcn_mfma_f32_16x16x32_f16(a1, bf1[j], zj, 0, 0, 0);
            s[j] = zj[0];            // rows broadcast -> any component/any lane is col c16
        }

        // ---- gather: unit u = l, gate g lives in tile 4*q + g at own column
        float gi = sel4(q, s[0], s[4], s[8],  s[12]) + tt[0];
        float gf = sel4(q, s[1], s[5], s[9],  s[13]) + tt[1];
        float gg = sel4(q, s[2], s[6], s[10], s[14]) + tt[2];
        float go = sel4(q, s[3], s[7], s[11], s[15]) + tt[3];

        float iv = sigm(gi);
        float fv = sigm(gf);
        float gv = tanh_(gg);
        float ov = sigm(go);
        c = fmaf(fv, c, iv * gv);
        h = ov * tanh_(c);           // lanes >= 50: gates are exactly 0 -> h stays 0

        // ---- scatter h -> A-frags: cvt once, 16 parallel bpermutes, pack pairs
        int hb = (int)__half_as_ushort(__float2half(h));
        int r0 = __builtin_amdgcn_ds_bpermute(ab +  0, hb);
        int r1 = __builtin_amdgcn_ds_bpermute(ab +  4, hb);
        int r2 = __builtin_amdgcn_ds_bpermute(ab +  8, hb);
        int r3 = __builtin_amdgcn_ds_bpermute(ab + 12, hb);
        int r4 = __builtin_amdgcn_ds_bpermute(ab + 16, hb);
        int r5 = __builtin_amdgcn_ds_bpermute(ab + 20, hb);
        int r6 = __builtin_amdgcn_ds_bpermute(ab + 24, hb);
        int r7 = __builtin_amdgcn_ds_bpermute(ab + 28, hb);
        int s0 = __builtin_amdgcn_ds_bpermute(ab + 128 +  0, hb);
        int s1 = __builtin_amdgcn_ds_bpermute(ab + 128 +  4, hb);
        int s2 = __builtin_amdgcn_ds_bpermute(ab + 128 +  8, hb);
        int s3 = __builtin_amdgcn_ds_bpermute(ab + 128 + 12, hb);
        int s4 = __builtin_amdgcn_ds_bpermute(ab + 128 + 16, hb);
        int s5 = __builtin_amdgcn_ds_bpermute(ab + 128 + 20, hb);
        int s6 = __builtin_amdgcn_ds_bpermute(ab + 128 + 24, hb);
        int s7 = __builtin_amdgcn_ds_bpermute(ab + 128 + 28, hb);

        union { uint4v u; half8 h; } p0, p1;
        p0.u = (uint4v){ (uint)r0 | ((uint)r1 << 16), (uint)r2 | ((uint)r3 << 16),
                         (uint)r4 | ((uint)r5 << 16), (uint)r6 | ((uint)r7 << 16) };
        p1.u = (uint4v){ (uint)s0 | ((uint)s1 << 16), (uint)s2 | ((uint)s3 << 16),
                         (uint)s4 | ((uint)s5 << 16), (uint)s6 | ((uint)s7 << 16) };
        a0 = p0.h;   // A[*, k= 0..31] = h[k]  (rows broadcast)
        a1 = p1.h;   // A[*, k=32..63] = h[k] (k>=50 junk x B-zeros = 0)

        tt = ttn; vA = vB; vB = vN;
    }

    // ---- epilogue MLP (once)
    hbuf[w][l] = h;                  // lane u holds h_u (f32); lanes>=50 hold 0
    __syncthreads();
    if (l < HID) {
        float a = b1[l];
        const float* wr = W1 + l * HID;
        const float* hp = hbuf[w];
        #pragma unroll 10
        for (int k = 0; k < HID; ++k) a = fmaf(wr[k], hp[k], a);
        zbuf[w][l] = fmaxf(a, 0.f);
    }
    __syncthreads();
    if (l == 0) {
        float a = b2[0];
        const float* zp = zbuf[w];
        #pragma unroll 10
        for (int j = 0; j < HID; ++j) a = fmaf(W2[j], zp[j], a);
        out[row] = a;
    }
}

extern "C" void kernel_launch(void* const* d_in, const int* in_sizes, int n_in,
                              void* d_out, int out_size, void* d_ws, size_t ws_size,
                              hipStream_t stream) {
    const int*   x     = (const int*)  d_in[0];
    const float* embed = (const float*)d_in[1];
    const float* W_ih  = (const float*)d_in[2];
    const float* W_hh  = (const float*)d_in[3];
    const float* b_ih  = (const float*)d_in[4];
    const float* b_hh  = (const float*)d_in[5];
    const float* W1    = (const float*)d_in[6];
    const float* b1    = (const float*)d_in[7];
    const float* W2    = (const float*)d_in[8];
    const float* b2    = (const float*)d_in[9];
    float* out = (float*)d_out;

    ushort* Bm = (ushort*)d_ws;                          // 256*64*2  = 32768 B
    float*  Tt = (float*)((char*)d_ws + NT * 16 * KP * 2); // 13*256*4 = 13312 B

    build_tabs<<<(NT * 16 * KP + VOC * 256 + NTHR - 1) / NTHR, NTHR, 0, stream>>>(
        embed, W_ih, W_hh, b_ih, b_hh, Bm, Tt);

    lstm_wave<<<NBLK, NTHR, 0, stream>>>(
        x, Bm, Tt, W1, b1, W2, b2, out);
}

// Round 2
// 773.637 us; speedup vs baseline: 1.7838x; 1.7838x over previous
//
#include <hip/hip_runtime.h>
#include <hip/hip_fp16.h>

#define T_SEQ 2048
#define HID   50
#define KP    64      // k: 0..49 = h, 50..62 = onehot, 63 = bias
#define MB    4       // batch rows per block
#define NBLK  512     // 2048 / MB -> 2 blocks/CU
#define NTHR  256     // 4 waves
#define HSTR  80      // ushorts per h row (160 B): conflict-free (2-way) pattern
#define BUFB  (MB*HSTR)   // ushorts per buffer = 320

typedef __attribute__((ext_vector_type(8))) _Float16 half8;
typedef __attribute__((ext_vector_type(4))) float    f32x4;

__device__ __forceinline__ ushort f16b(float f){ return __half_as_ushort(__float2half(f)); }
__device__ __forceinline__ float rcp_(float x){ return __builtin_amdgcn_rcpf(x); }
__device__ __forceinline__ float sigm(float x){ return rcp_(1.f + __expf(-x)); }
__device__ __forceinline__ float tanh_(float x){ return fmaf(2.f, rcp_(1.f + __expf(-2.f*x)), -1.f); }
// pick among 4 values by per-lane q in [0,4): 3 cndmask (no dynamic vector index)
__device__ __forceinline__ float sel4(int q, float a, float b, float c, float d){
    float x = (q == 0) ? a : b;
    float y = (q == 2) ? c : d;
    return (q < 2) ? x : y;
}

// Bm[256 cols][64 k] f16.  col = w*64 + g*16 + c16 encodes unit u = w*16+c16, gate g.
// Row r = g*50+u of the gate matrix:  k<50: W_hh[r][k];  k in 50..62: Ttab[k-50][r]
// (= embed[v]·W_ih[r], one-hot folded into K);  k==63: b_ih[r]+b_hh[r];  pad cols zero.
__global__ void build_B(const float* __restrict__ embed, const float* __restrict__ Wih,
                        const float* __restrict__ Whh, const float* __restrict__ bih,
                        const float* __restrict__ bhh, ushort* __restrict__ Bm) {
    int idx = blockIdx.x * blockDim.x + threadIdx.x;
    if (idx >= 256 * KP) return;
    int col = idx >> 6, k = idx & 63;
    int wq = col >> 6, g = (col >> 4) & 3, cc = col & 15;
    int u = wq * 16 + cc;
    ushort v = 0;
    if (u < HID) {
        int r = g * HID + u;
        if (k < HID) {
            v = f16b(Whh[r * HID + k]);
        } else if (k < 63) {
            float s = 0.f;
            for (int e = 0; e < HID; ++e)
                s = fmaf(embed[(k - 50) * HID + e], Wih[r * HID + e], s);
            v = f16b(s);
        } else {
            v = f16b(bih[r] + bhh[r]);
        }
    }
    Bm[idx] = v;
}

// MB=4 rows/block, 4 waves, 2 blocks/CU. A rows = h[row&3] (dup x4), so every lane's
// f32x4 holds all 4 rows of (unit 16w+c16, gate j) -> 1 activation per lane, no G buffer,
// no bpermute, 1 barrier/step. Double-buffered h in LDS.
__global__ __launch_bounds__(NTHR, 2) void lstm4(
    const int*    __restrict__ x,
    const ushort* __restrict__ Bm,
    const float*  __restrict__ W1,
    const float*  __restrict__ b1,
    const float*  __restrict__ W2,
    const float*  __restrict__ b2,
    float*        __restrict__ out)
{
    const int t   = threadIdx.x;
    const int w   = t >> 6;
    const int l   = t & 63;
    const int q   = l >> 4;
    const int c16 = l & 15;
    const int u   = w * 16 + c16;          // unit handled by this lane (row = q)

    __shared__ __align__(16) ushort hbuf[2 * BUFB];   // 1280 B
    __shared__ float zb[HID * MB];

    // B fragments: wave w owns tiles 4w..4w+3 (gate j = tile&3), col c16
    half8 bf[4][2];
    {
        const ushort* bp = Bm + (w * 64 + c16) * KP + q * 8;
        #pragma unroll
        for (int j = 0; j < 4; ++j) {
            bf[j][0] = *(const half8*)(bp + j * 16 * KP);
            bf[j][1] = *(const half8*)(bp + j * 16 * KP + 32);
        }
    }
    #pragma unroll
    for (int j = 0; j < 4; ++j)
        asm volatile("" : "+v"(bf[j][0]), "+v"(bf[j][1]));

    for (int i = t; i < 2 * BUFB; i += NTHR) hbuf[i] = 0;

    const int  row0 = blockIdx.x * MB;
    const long xb   = (long)row0 * T_SEQ;
    int t0r = 0, t1r = 0, t2r = 0;
    __syncthreads();
    if (t < MB) {
        int tk0 = x[xb + (long)t * T_SEQ + 0];
        int tk1 = x[xb + (long)t * T_SEQ + 1];
        hbuf[0 * BUFB + t * HSTR + 63] = 0x3C00;        // bias slot = 1.0
        hbuf[1 * BUFB + t * HSTR + 63] = 0x3C00;
        hbuf[0 * BUFB + t * HSTR + 50 + tk0] = 0x3C00;  // onehot step 0
        hbuf[1 * BUFB + t * HSTR + 50 + tk1] = 0x3C00;  // onehot step 1
        t0r = tk1; t1r = tk0; t2r = tk1;                // clear(t0)/set(t2) window
    }
    __syncthreads();

    // A-frag read base: row (c16&3), k = P*0 + q*8 (+32 for a1); 2-way banks = free
    const ushort* ar  = hbuf + (c16 & 3) * HSTR + q * 8;
    ushort*       wr_ = hbuf + q * HSTR + u;            // h write: row q, unit u

    float cst = 0.f;

#define STEP(P) do {                                                              \
        int pf = 0;                                                               \
        if (t < MB) {                                                             \
            int it = step + 2 + (P); if (it > T_SEQ - 1) it = T_SEQ - 1;          \
            pf = x[xb + (long)t * T_SEQ + it];                                    \
        }                                                                         \
        half8 a0 = *(const half8*)(ar + (P) * BUFB);                              \
        half8 a1 = *(const half8*)(ar + (P) * BUFB + 32);                         \
        const f32x4 zz = {0.f, 0.f, 0.f, 0.f};                                    \
        f32x4 z0 = __builtin_amdgcn_mfma_f32_16x16x32_f16(a0, bf[0][0], zz,0,0,0);\
        z0 = __builtin_amdgcn_mfma_f32_16x16x32_f16(a1, bf[0][1], z0, 0,0,0);     \
        f32x4 z1 = __builtin_amdgcn_mfma_f32_16x16x32_f16(a0, bf[1][0], zz,0,0,0);\
        z1 = __builtin_amdgcn_mfma_f32_16x16x32_f16(a1, bf[1][1], z1, 0,0,0);     \
        f32x4 z2 = __builtin_amdgcn_mfma_f32_16x16x32_f16(a0, bf[2][0], zz,0,0,0);\
        z2 = __builtin_amdgcn_mfma_f32_16x16x32_f16(a1, bf[2][1], z2, 0,0,0);     \
        f32x4 z3 = __builtin_amdgcn_mfma_f32_16x16x32_f16(a0, bf[3][0], zz,0,0,0);\
        z3 = __builtin_amdgcn_mfma_f32_16x16x32_f16(a1, bf[3][1], z3, 0,0,0);     \
        float gi = sel4(q, z0[0], z0[1], z0[2], z0[3]);                           \
        float gf = sel4(q, z1[0], z1[1], z1[2], z1[3]);                           \
        float gg = sel4(q, z2[0], z2[1], z2[2], z2[3]);                           \
        float go = sel4(q, z3[0], z3[1], z3[2], z3[3]);                           \
        float iv = sigm(gi), fv = sigm(gf), gv = tanh_(gg), ov = sigm(go);        \
        cst = fmaf(fv, cst, iv * gv);                                             \
        float hh = ov * tanh_(cst);                                               \
        if (u < HID) wr_[(1 - (P)) * BUFB] = f16b(hh);                            \
        if (t < MB) {                                                             \
            ushort* hb = hbuf + (1 - (P)) * BUFB + t * HSTR + 50;                 \
            hb[t0r] = 0;                                                          \
            hb[t2r] = 0x3C00;                                                     \
            t0r = t1r; t1r = t2r; t2r = pf;                                       \
        }                                                                         \
        __syncthreads();                                                          \
    } while (0)

    #pragma unroll 1
    for (int step = 0; step < T_SEQ; step += 2) {
        STEP(0);
        STEP(1);
    }
#undef STEP

    // Epilogue MLP: final h is in buffer 0 (last step wrote it), already synced.
    if (t < MB * HID) {
        int m = t & 3, uu = t >> 2;
        float a = b1[uu];
        const ushort* hr = hbuf + m * HSTR;
        #pragma unroll 10
        for (int k = 0; k < HID; ++k)
            a = fmaf(W1[uu * HID + k], __half2float(__ushort_as_half(hr[k])), a);
        zb[uu * MB + m] = fmaxf(a, 0.f);
    }
    __syncthreads();
    if (t < MB) {
        float a = b2[0];
        #pragma unroll 10
        for (int j = 0; j < HID; ++j)
            a = fmaf(W2[j], zb[j * MB + t], a);
        out[row0 + t] = a;
    }
}

extern "C" void kernel_launch(void* const* d_in, const int* in_sizes, int n_in,
                              void* d_out, int out_size, void* d_ws, size_t ws_size,
                              hipStream_t stream) {
    const int*   x     = (const int*)  d_in[0];
    const float* embed = (const float*)d_in[1];
    const float* W_ih  = (const float*)d_in[2];
    const float* W_hh  = (const float*)d_in[3];
    const float* b_ih  = (const float*)d_in[4];
    const float* b_hh  = (const float*)d_in[5];
    const float* W1    = (const float*)d_in[6];
    const float* b1    = (const float*)d_in[7];
    const float* W2    = (const float*)d_in[8];
    const float* b2    = (const float*)d_in[9];
    float* out = (float*)d_out;

    ushort* Bm = (ushort*)d_ws;   // 256*64*2 = 32768 B scratch

    build_B<<<(256 * KP + NTHR - 1) / NTHR, NTHR, 0, stream>>>(
        embed, W_ih, W_hh, b_ih, b_hh, Bm);

    lstm4<<<NBLK, NTHR, 0, stream>>>(
        x, Bm, W1, b1, W2, b2, out);
}